// Round 1
// baseline (482.158 us; speedup 1.0000x reference)
//
#include <hip/hip_runtime.h>
#include <stdint.h>

// Spiking ConvColumn: temporal PWL-response conv + winner-takes-all.
// Sizes (fixed by the reference):
//   input_spikes [16, 2, 64, 64, 100] fp32 (binary)
//   weight       [32, 2, 3, 3]        fp32 in [0,1]
//   output       [16, 32, 31, 31, 149] fp32 (one-hot spikes)
#define NXS 31
#define NYS 31
#define BB 16
#define NTRAIN 18      // C_in * 3 * 3
#define TBL_STRIDE 104 // 101 entries padded to 16B multiple
#define TP 149         // output time steps
#define TT 100         // input time steps

__global__ void snn_conv_wta(const float* __restrict__ in,
                             const float* __restrict__ weight,
                             float* __restrict__ out)
{
    // packed prefix tables: entry k = (C[k]<<16) | M[k],
    // C[k] = #spikes before time k, M[k] = sum of spike times before k.
    __shared__ __align__(16) uint32_t tbl[2 * NTRAIN * TBL_STRIDE];

    const int lane = threadIdx.x;   // 0..63
    const int half = lane >> 5;     // which of the 2 sites this lane serves
    const int ch   = lane & 31;     // output channel
    const int site0 = blockIdx.x * 2;

    // ---- per-channel response params (no LDS dependency) ----
    // r(tau) = tau/16            for tau <= m = floor(16w)
    //        = (48w - tau)/32    for m < tau <= n = ceil(48w)-1
    //        = 0                 beyond
    float wA[NTRAIN];
    int   mA[NTRAIN], nA[NTRAIN];
    {
        const float* wrow = weight + ch * NTRAIN; // [o][i][ky][kx] flat
#pragma unroll
        for (int tr = 0; tr < NTRAIN; ++tr) {
            float w = wrow[tr];
            float a48 = 48.0f * w;
            int m = (int)floorf(16.0f * w);
            int n = (int)ceilf(a48) - 1;
            if (n < m) n = m;          // w==0 edge: empty segment 2
            wA[tr] = a48;
            mA[tr] = m;
            nA[tr] = n;
        }
    }

    // ---- phase 1: build prefix tables (36 active lanes: site x train) ----
    if (lane < 2 * NTRAIN) {
        const int s_local = (lane >= NTRAIN) ? 1 : 0;
        const int tr = lane - s_local * NTRAIN;
        const int s_id = site0 + s_local;
        const int x = s_id % NXS;
        const int y = (s_id / NXS) % NYS;
        const int b = s_id / (NXS * NYS);
        const int ci = tr / 9;
        const int ky = (tr % 9) / 3;
        const int kx = tr % 3;
        const int h = 2 * y + ky;      // no spatial padding, stride 2
        const int wc = 2 * x + kx;
        // row of 100 floats, 400B => 16B aligned
        const float4* row = (const float4*)(in +
            (size_t)(((b * 2 + ci) * 64 + h) * 64 + wc) * TT);
        uint32_t* t = tbl + (s_local * NTRAIN + tr) * TBL_STRIDE;
        int c_run = 0, m_run = 0;
        int u = 0;
#pragma unroll 5
        for (int chunk = 0; chunk < 25; ++chunk) {
            float4 v = row[chunk];
            uint32_t e0 = (uint32_t)((c_run << 16) | m_run);
            if (v.x > 0.5f) { c_run++; m_run += u; } u++;
            uint32_t e1 = (uint32_t)((c_run << 16) | m_run);
            if (v.y > 0.5f) { c_run++; m_run += u; } u++;
            uint32_t e2 = (uint32_t)((c_run << 16) | m_run);
            if (v.z > 0.5f) { c_run++; m_run += u; } u++;
            uint32_t e3 = (uint32_t)((c_run << 16) | m_run);
            if (v.w > 0.5f) { c_run++; m_run += u; } u++;
            ((uint4*)t)[chunk] = make_uint4(e0, e1, e2, e3);
        }
        t[TT] = (uint32_t)((c_run << 16) | m_run);
    }
    __syncthreads();

    // ---- phase 2: WTA scan with on-demand potential evaluation ----
    const int s_id = site0 + half;
    const int x = s_id % NXS;
    const int y = (s_id / NXS) % NYS;
    const int b = s_id / (NXS * NYS);
    const uint32_t* T = tbl + half * NTRAIN * TBL_STRIDE;
    float* orow = out + (size_t)(((b * 32 + ch) * NXS + y) * NYS + x) * TP;

    int dep = 0;
    for (int tp = 0; tp < TP; ++tp) {
        if (dep == 0) {
            const int t1 = tp - 1;            // u = t1 - tau
            const float ft1 = (float)t1;
            const int i0 = (tp < TT) ? tp : TT;   // uniform -> LDS broadcast
            float pot = 0.0f;
#pragma unroll
            for (int tr = 0; tr < NTRAIN; ++tr) {
                const uint32_t* tt = T + tr * TBL_STRIDE;
                int i1 = t1 - mA[tr]; i1 = i1 < 0 ? 0 : (i1 > TT ? TT : i1);
                int i2 = t1 - nA[tr]; i2 = i2 < 0 ? 0 : (i2 > TT ? TT : i2);
                uint32_t p0 = tt[i0];
                uint32_t p1 = tt[i1];
                uint32_t p2 = tt[i2];
                // rising segment: sum s[u]*(t1-u)/16 over u in [t1-m, t1]
                float dc1 = (float)(int)((p0 >> 16) - (p1 >> 16));
                float dm1 = (float)(int)((p0 & 0xffffu) - (p1 & 0xffffu));
                // falling segment: sum s[u]*(48w - (t1-u))/32 over [t1-n, t1-1-m]
                float dc2 = (float)(int)((p1 >> 16) - (p2 >> 16));
                float dm2 = (float)(int)((p1 & 0xffffu) - (p2 & 0xffffu));
                pot += (ft1 * dc1 - dm1) * 0.0625f;
                pot += ((wA[tr] - ft1) * dc2 + dm2) * 0.03125f;
            }
            // argmax over the 32 lanes of this half-wave; ties -> lowest ch
            float v = pot; int c = ch;
#pragma unroll
            for (int mk = 16; mk >= 1; mk >>= 1) {
                float vo = __shfl_xor(v, mk);
                int co   = __shfl_xor(c, mk);
                if (vo > v || (vo == v && co < c)) { v = vo; c = co; }
            }
            if (v > 5.4f) {
                if (c == ch) orow[tp] = 1.0f;  // sparse one-hot write
                dep = 47;                       // clip(0 + 48 - 1, 0, 47)
            }
            // no spike: dep stays 0 (clip(-1,0,47) = 0)
        } else {
            dep--;
        }
    }
}

extern "C" void kernel_launch(void* const* d_in, const int* in_sizes, int n_in,
                              void* d_out, int out_size, void* d_ws, size_t ws_size,
                              hipStream_t stream) {
    const float* in = (const float*)d_in[0];   // input_spikes
    const float* wt = (const float*)d_in[1];   // weight
    float* out = (float*)d_out;

    // output is ~99.99% zeros: clear it, kernel writes only the spikes
    hipMemsetAsync(d_out, 0, (size_t)out_size * sizeof(float), stream);

    const int n_sites = BB * NXS * NYS;        // 15376
    dim3 grid(n_sites / 2), block(64);
    hipLaunchKernelGGL(snn_conv_wta, grid, block, 0, stream, in, wt, out);
}

// Round 2
// 423.675 us; speedup vs baseline: 1.1380x; 1.1380x over previous
//
#include <hip/hip_runtime.h>
#include <stdint.h>

// Spiking ConvColumn: temporal PWL-response conv + winner-takes-all.
//   input_spikes [16, 2, 64, 64, 100] fp32 (binary)
//   weight       [32, 2, 3, 3]        fp32 in [0,1]
//   output       [16, 32, 31, 31, 149] fp32 (one-hot spikes)
#define NXS 31
#define NYS 31
#define NTRAIN 18      // C_in * 3 * 3
#define NT_HALF 9
#define TBL_STRIDE 101 // 101 entries; 101 mod 32 = 5, gcd(5,32)=1 -> conflict-free
#define TP 149         // output time steps
#define TT 100         // input time steps

// One site per 64-lane wave. Lanes 0-31: channels x trains 0-8;
// lanes 32-63: same channels x trains 9-17. Block = 2 waves = 2 sites.
__global__ __launch_bounds__(128) void snn_conv_wta(
    const float* __restrict__ in,
    const float* __restrict__ weight,
    float* __restrict__ out)
{
    // packed prefix tables per site: entry k = (C[k]<<16) | M[k]
    // C[k] = #spikes at times < k, M[k] = sum of those spike times.
    __shared__ uint32_t tbl[2 * NTRAIN * TBL_STRIDE];

    const int tid  = threadIdx.x;
    const int wave = tid >> 6;
    const int lane = tid & 63;
    const int half = lane >> 5;
    const int ch   = lane & 31;
    const int s_id = blockIdx.x * 2 + wave;
    const int x = s_id % NXS;
    const int y = (s_id / NXS) % NYS;
    const int b = s_id / (NXS * NYS);

    uint32_t* T = tbl + wave * NTRAIN * TBL_STRIDE;

    // ---- phase 1: 18 lanes/wave build prefix tables (scalar LDS writes,
    // banks (5*tr + k) % 32 are distinct across the 18 active lanes) ----
    if (lane < NTRAIN) {
        const int tr = lane;
        const int ci = tr / 9;
        const int ky = (tr % 9) / 3;
        const int kx = tr % 3;
        const int h  = 2 * y + ky;          // valid conv, spatial stride 2
        const int wc = 2 * x + kx;
        const float4* row = (const float4*)(in +
            (size_t)(((b * 2 + ci) * 64 + h) * 64 + wc) * TT); // 400B-aligned
        uint32_t* t = T + tr * TBL_STRIDE;
        int c_run = 0, m_run = 0, u = 0;
#pragma unroll 5
        for (int chunk = 0; chunk < 25; ++chunk) {
            float4 v = row[chunk];
            t[u] = (uint32_t)((c_run << 16) | m_run);
            if (v.x > 0.5f) { c_run++; m_run += u; } u++;
            t[u] = (uint32_t)((c_run << 16) | m_run);
            if (v.y > 0.5f) { c_run++; m_run += u; } u++;
            t[u] = (uint32_t)((c_run << 16) | m_run);
            if (v.z > 0.5f) { c_run++; m_run += u; } u++;
            t[u] = (uint32_t)((c_run << 16) | m_run);
            if (v.w > 0.5f) { c_run++; m_run += u; } u++;
        }
        t[TT] = (uint32_t)((c_run << 16) | m_run);
    }
    __syncthreads();

    // ---- per-lane response params for this lane's 9 trains ----
    // r(tau) = tau/16 for tau <= m = floor(16w); (48w-tau)/32 for m<tau<=n;
    // n = ceil(48w)-1.
    float wA[NT_HALF]; int mA[NT_HALF], nA[NT_HALF];
    {
        const float* wrow = weight + ch * NTRAIN + half * NT_HALF;
#pragma unroll
        for (int j = 0; j < NT_HALF; ++j) {
            float w = wrow[j];
            float a48 = 48.0f * w;
            int m = (int)floorf(16.0f * w);
            int n = (int)ceilf(a48) - 1;
            if (n < m) n = m;
            wA[j] = a48; mA[j] = m; nA[j] = n;
        }
    }
    const uint32_t* Th = T + half * NT_HALF * TBL_STRIDE;

    // ---- phase 2: jump-scan WTA (spike => skip 48 steps, exact dep calc) ----
    uint64_t msk0 = 0, msk1 = 0;
    uint32_t msk2 = 0;
    int tp = 0;
    while (tp < TP) {
        const int t1 = tp - 1;
        const float ft1 = (float)t1;
        const int i0 = (tp < TT) ? tp : TT;   // wave-uniform -> LDS broadcast
        float pot = 0.0f;
#pragma unroll
        for (int j = 0; j < NT_HALF; ++j) {
            const uint32_t* tt = Th + j * TBL_STRIDE;
            int i1 = t1 - mA[j]; i1 = i1 < 0 ? 0 : (i1 > TT ? TT : i1);
            int i2 = t1 - nA[j]; i2 = i2 < 0 ? 0 : (i2 > TT ? TT : i2);
            uint32_t p0 = tt[i0];
            uint32_t p1 = tt[i1];
            uint32_t p2 = tt[i2];
            // rising: sum s[u]*(t1-u)/16, u in [t1-m, t1]
            float dc1 = (float)(int)((p0 >> 16) - (p1 >> 16));
            float dm1 = (float)(int)((p0 & 0xffffu) - (p1 & 0xffffu));
            // falling: sum s[u]*(48w-(t1-u))/32, u in [t1-n, t1-1-m]
            float dc2 = (float)(int)((p1 >> 16) - (p2 >> 16));
            float dm2 = (float)(int)((p1 & 0xffffu) - (p2 & 0xffffu));
            pot += (ft1 * dc1 - dm1) * 0.0625f;
            pot += ((wA[j] - ft1) * dc2 + dm2) * 0.03125f;
        }
        pot += __shfl_xor(pot, 32);           // combine the two train halves

        // argmax over 32 channels (both halves hold identical copies);
        // ties -> lowest channel, matching jnp.argmax
        float v = pot; int c = ch;
#pragma unroll
        for (int mk = 16; mk >= 1; mk >>= 1) {
            float vo = __shfl_xor(v, mk);
            int co   = __shfl_xor(c, mk);
            if (vo > v || (vo == v && co < c)) { v = vo; c = co; }
        }
        if (v > 5.4f) {
            if (c == ch) {                    // record one-hot spike bit
                if (tp < 64)       msk0 |= 1ull << tp;
                else if (tp < 128) msk1 |= 1ull << (tp - 64);
                else               msk2 |= 1u   << (tp - 128);
            }
            tp += 48;                         // dep=47 => next eligible tp+48
        } else {
            tp += 1;
        }
    }

    // ---- epilogue: dense coalesced write of all 32 rows (no memset pass) ----
    const size_t base0 = ((size_t)(b * 32) * NXS * NYS + (size_t)y * NYS + x) * TP;
    const size_t cstride = (size_t)NXS * NYS * TP;  // 143189
#pragma unroll 4
    for (int c = 0; c < 32; ++c) {
        uint64_t a0 = __shfl((unsigned long long)msk0, c);
        uint64_t a1 = __shfl((unsigned long long)msk1, c);
        uint32_t a2 = __shfl((unsigned int)msk2, c);
        float* r = out + base0 + (size_t)c * cstride;
        r[lane]      = ((a0 >> lane) & 1ull) ? 1.0f : 0.0f;   // tp = 0..63
        r[64 + lane] = ((a1 >> lane) & 1ull) ? 1.0f : 0.0f;   // tp = 64..127
        if (lane < TP - 128)
            r[128 + lane] = ((a2 >> lane) & 1u) ? 1.0f : 0.0f; // tp = 128..148
    }
}

extern "C" void kernel_launch(void* const* d_in, const int* in_sizes, int n_in,
                              void* d_out, int out_size, void* d_ws, size_t ws_size,
                              hipStream_t stream) {
    const float* in = (const float*)d_in[0];   // input_spikes
    const float* wt = (const float*)d_in[1];   // weight
    float* out = (float*)d_out;

    const int n_sites = 16 * NXS * NYS;        // 15376, 2 sites per block
    dim3 grid(n_sites / 2), block(128);
    hipLaunchKernelGGL(snn_conv_wta, grid, block, 0, stream, in, wt, out);
}